// Round 4
// baseline (321.201 us; speedup 1.0000x reference)
//
#include <hip/hip_runtime.h>

#define HID 2048
#define NEXP 64
#define NTOK 16384
#define TM 32            // tokens per block (one 32-row MFMA tile)
#define NTHREADS 512     // 8 waves
#define NPH 16           // K-phases (2 chunks of 64 floats each per phase)
#define PHB 16384        // bytes staged per phase (2 chunks x 32 rows x 256 B)
#define TPW 4            // tokens per wave in epilogue (TM / 8)
#define NBLK (NTOK / TM) // 512
#define WS_W_OFF 1024    // W planes start here in d_ws
#define CHUNK_B 24576    // 4 ksteps * 3 planes * 2 halves * 1024 B

// out layout (f32): weights [0,32768) | indices [32768,65536) | aux 65536 | counts [65537,65601)
#define OUT_IDX_OFF (2 * NTOK)
#define OUT_AUX_OFF (4 * NTOK)
#define OUT_CNT_OFF (4 * NTOK + 1)

typedef __attribute__((ext_vector_type(8))) short bhalf8;    // 8 bf16 = 4 VGPRs (A/B frag)
typedef __attribute__((ext_vector_type(16))) float f32x16;   // 32x32 C/D frag

// async 1KB global->LDS stage: per-lane 16B source, LDS dest = wave-uniform base + lane*16
__device__ __forceinline__ void stage1k(const void* g, void* l) {
    __builtin_amdgcn_global_load_lds((const __attribute__((address_space(1))) void*)g,
                                     (__attribute__((address_space(3))) void*)l, 16, 0, 0);
}

// Exact 3-way RNE bf16 split (for W, precomputed): v == h1+h2+h3 exactly.
__device__ __forceinline__ void split3(float v, unsigned short& h1, unsigned short& h2, unsigned short& h3) {
    unsigned int u = __float_as_uint(v);
    unsigned int r1 = (u + 0x7FFFu + ((u >> 16) & 1u)) & 0xFFFF0000u;
    float f1 = __uint_as_float(r1);
    float d1 = v - f1;
    unsigned int u2 = __float_as_uint(d1);
    unsigned int r2 = (u2 + 0x7FFFu + ((u2 >> 16) & 1u)) & 0xFFFF0000u;
    float f2 = __uint_as_float(r2);
    float d2 = d1 - f2;
    h1 = (unsigned short)(r1 >> 16);
    h2 = (unsigned short)(r2 >> 16);
    h3 = (unsigned short)(__float_as_uint(d2) >> 16);
}

// Truncating 3-plane split of 8 fp32 -> three bf16x8 A-frags, in registers.
__device__ __forceinline__ void xsplit(float4 va, float4 vb, bhalf8& o1, bhalf8& o2, bhalf8& o3) {
    float f[8] = {va.x, va.y, va.z, va.w, vb.x, vb.y, vb.z, vb.w};
    union U { bhalf8 v; unsigned int u[4]; } u1, u2, u3;
#pragma unroll
    for (int t = 0; t < 4; t++) {
        float a = f[2 * t], b = f[2 * t + 1];
        unsigned int ua = __float_as_uint(a), ub = __float_as_uint(b);
        float da = a - __uint_as_float(ua & 0xFFFF0000u);
        float db = b - __uint_as_float(ub & 0xFFFF0000u);
        unsigned int uda = __float_as_uint(da), udb = __float_as_uint(db);
        float da2 = da - __uint_as_float(uda & 0xFFFF0000u);
        float db2 = db - __uint_as_float(udb & 0xFFFF0000u);
        u1.u[t] = (ua >> 16) | (ub & 0xFFFF0000u);
        u2.u[t] = (uda >> 16) | (udb & 0xFFFF0000u);
        u3.u[t] = (__float_as_uint(da2) >> 16) | (__float_as_uint(db2) & 0xFFFF0000u);
    }
    o1 = u1.v; o2 = u2.v; o3 = u3.v;
}

// ---- pre-kernel: split W into 3 bf16 planes in coalesced B-fragment layout ----
__global__ __launch_bounds__(64) void wsplit_kernel(const float* __restrict__ W,
                                                    char* __restrict__ wq,
                                                    float* __restrict__ wsf) {
    if (blockIdx.x < 3) wsf[blockIdx.x * 64 + threadIdx.x] = 0.f;   // zero accum[0,192)
    int idx8 = (blockIdx.x * 64 + threadIdx.x) * 8;   // 16384 threads x 8 elems
    int e = idx8 >> 11;
    int k0 = idx8 & 2047;                // octet-aligned k
    int c = k0 >> 6, ks = (k0 >> 4) & 3, half = (k0 >> 3) & 1;
    int g = e >> 5, l = (e & 31) + 32 * half;
    const float4* wp = (const float4*)(W + (size_t)e * HID + k0);
    float4 v0 = wp[0], v1 = wp[1];
    float f[8] = {v0.x, v0.y, v0.z, v0.w, v1.x, v1.y, v1.z, v1.w};
    unsigned int p1[4], p2[4], p3[4];
#pragma unroll
    for (int t = 0; t < 4; t++) {
        unsigned short a1, a2, a3, b1, b2, b3;
        split3(f[2 * t], a1, a2, a3);
        split3(f[2 * t + 1], b1, b2, b3);
        p1[t] = (unsigned int)a1 | ((unsigned int)b1 << 16);
        p2[t] = (unsigned int)a2 | ((unsigned int)b2 << 16);
        p3[t] = (unsigned int)a3 | ((unsigned int)b3 << 16);
    }
    char* base = wq + (size_t)(((c * 4 + ks) * 3 + 0) * 2 + g) * 1024 + l * 16;
    *(uint4*)(base)        = make_uint4(p1[0], p1[1], p1[2], p1[3]);   // plane 1
    *(uint4*)(base + 2048) = make_uint4(p2[0], p2[1], p2[2], p2[3]);   // plane 2
    *(uint4*)(base + 4096) = make_uint4(p3[0], p3[1], p3[2], p3[3]);   // plane 3
}

__global__ __launch_bounds__(NTHREADS, 2) void router_main(
    const float* __restrict__ x, const char* __restrict__ wq,
    float* __restrict__ out, float* __restrict__ wsf)
{
    // double-buffered x staging: [2][2 chunks][32 rows][16 granules of 16B], linear dest,
    // source granule pre-swizzled g^(row&15) so ds_read_b128 frags are ~2-way conflict free
    __shared__ __align__(16) char xs[2 * PHB];   // 32 KB
    __shared__ float slab[TM * 68];              // 8.7 KB accumulated logits
    __shared__ float scount[NEXP];
    __shared__ float sprob[NEXP];
    __shared__ int slast;

    const int tid = threadIdx.x;
    const int w = tid >> 6;        // wave id: ks = w>>1, expert group = w&1
    const int lane = tid & 63;
    const int r = lane & 31;       // A row (token); B expert within group
    const int h = lane >> 5;       // k-octet half
    const int n0 = blockIdx.x * TM;
    const int ksw = w >> 1, g = w & 1;

    // zero logit accumulator + stats
    for (int i = tid; i < TM * 68; i += NTHREADS) slab[i] = 0.f;
    if (tid < NEXP) { scount[tid] = 0.f; sprob[tid] = 0.f; }

    // staging source: thread t covers row t>>4, LDS granule t&15, global granule (t&15)^(row&15)
    const int srow = tid >> 4;
    const char* gsrc = (const char*)x + (size_t)(n0 + srow) * (HID * 4)
                     + (((tid & 15) ^ (srow & 15)) << 4);
    char* ldst = xs;               // wave-uniform LDS bases used below: + buf*PHB + ci*8192 + w*1024
    (void)ldst;

    // fragment-read offsets within a staged chunk (row-major 256B rows, swizzled granule)
    const int G0 = ksw * 4 + h * 2;
    const int ro = r * 256 + ((G0 ^ (r & 15)) << 4);    // pva; pvb at ro^16 (G0 is even)

    // wq base for this wave's (ks, group): 3 planes at +0/+2048/+4096, per chunk + c*CHUNK_B
    const char* wbase = wq + ksw * 6144 + g * 1024 + lane * 16;

    f32x16 acc;
#pragma unroll
    for (int i = 0; i < 16; i++) acc[i] = 0.f;

    // ---- prologue: stage phase 0 (chunks 0,1) + load its B-frags ----
    stage1k(gsrc + 0 * 256, xs + 0 * 8192 + w * 1024);
    stage1k(gsrc + 1 * 256, xs + 1 * 8192 + w * 1024);
    bhalf8 Bc[6];
#pragma unroll
    for (int ci = 0; ci < 2; ci++)
#pragma unroll
        for (int p = 0; p < 3; p++)
            Bc[ci * 3 + p] = *(const bhalf8*)(wbase + (size_t)ci * CHUNK_B + p * 2048);
    __syncthreads();   // drains stages (compiler emits vmcnt(0) before s_barrier)

    // ---- main loop: 16 phases x 2 chunks, 1 barrier per phase ----
#pragma unroll 1
    for (int p = 0; p < NPH; ++p) {
        const char* bc = xs + (p & 1) * PHB;
        // 1) read both chunks' A-frag float4s first (before touching the other buffer)
        float4 va0 = *(const float4*)(bc + 0 * 8192 + ro);
        float4 vb0 = *(const float4*)(bc + 0 * 8192 + (ro ^ 16));
        float4 va1 = *(const float4*)(bc + 1 * 8192 + ro);
        float4 vb1 = *(const float4*)(bc + 1 * 8192 + (ro ^ 16));
        // 2) issue next phase's staging + B-frag loads (latency hides under step 3)
        bhalf8 Bn[6];
        if (p < NPH - 1) {
            char* bn = xs + ((p + 1) & 1) * PHB;
            const int c2 = 2 * p + 2;
            stage1k(gsrc + (size_t)c2 * 256, bn + 0 * 8192 + w * 1024);
            stage1k(gsrc + (size_t)(c2 + 1) * 256, bn + 1 * 8192 + w * 1024);
#pragma unroll
            for (int ci = 0; ci < 2; ci++)
#pragma unroll
                for (int pl = 0; pl < 3; pl++)
                    Bn[ci * 3 + pl] = *(const bhalf8*)(wbase + (size_t)(c2 + ci) * CHUNK_B + pl * 2048);
        }
        // 3) compute both chunks with current B-frags
        {
            bhalf8 A1, A2, A3;
            xsplit(va0, vb0, A1, A2, A3);
            acc = __builtin_amdgcn_mfma_f32_32x32x16_bf16(A1, Bc[0], acc, 0, 0, 0);
            acc = __builtin_amdgcn_mfma_f32_32x32x16_bf16(A1, Bc[1], acc, 0, 0, 0);
            acc = __builtin_amdgcn_mfma_f32_32x32x16_bf16(A2, Bc[0], acc, 0, 0, 0);
            acc = __builtin_amdgcn_mfma_f32_32x32x16_bf16(A1, Bc[2], acc, 0, 0, 0);
            acc = __builtin_amdgcn_mfma_f32_32x32x16_bf16(A2, Bc[1], acc, 0, 0, 0);
            acc = __builtin_amdgcn_mfma_f32_32x32x16_bf16(A3, Bc[0], acc, 0, 0, 0);
        }
        {
            bhalf8 A1, A2, A3;
            xsplit(va1, vb1, A1, A2, A3);
            acc = __builtin_amdgcn_mfma_f32_32x32x16_bf16(A1, Bc[3], acc, 0, 0, 0);
            acc = __builtin_amdgcn_mfma_f32_32x32x16_bf16(A1, Bc[4], acc, 0, 0, 0);
            acc = __builtin_amdgcn_mfma_f32_32x32x16_bf16(A2, Bc[3], acc, 0, 0, 0);
            acc = __builtin_amdgcn_mfma_f32_32x32x16_bf16(A1, Bc[5], acc, 0, 0, 0);
            acc = __builtin_amdgcn_mfma_f32_32x32x16_bf16(A2, Bc[4], acc, 0, 0, 0);
            acc = __builtin_amdgcn_mfma_f32_32x32x16_bf16(A3, Bc[3], acc, 0, 0, 0);
        }
        if (p < NPH - 1) {
#pragma unroll
            for (int q = 0; q < 6; q++) Bc[q] = Bn[q];
        }
        __syncthreads();   // buffer handoff (also drains next-phase stages; residual covered by step 3)
    }

    // ---- combine: accumulate partial tiles via LDS atomics ----
    // C/D 32x32 layout: col = lane&31, row = (reg&3) + 8*(reg>>2) + 4*(lane>>5)  [m74/m101]
#pragma unroll
    for (int reg = 0; reg < 16; reg++) {
        int row = (reg & 3) + 8 * (reg >> 2) + 4 * h;
        atomicAdd(&slab[row * 68 + g * 32 + r], acc[reg]);
    }
    __syncthreads();

    // ---- wave-parallel epilogue: wave w handles tokens w*TPW .. w*TPW+3 ----
    const float* logits = slab;
    float pacc = 0.f;   // per-lane (expert=lane) softmax-prob sum over this wave's tokens
#pragma unroll 1
    for (int j = 0; j < TPW; j++) {
        const int t = w * TPW + j;
        const float v = logits[t * 68 + lane];
        float m1 = v, m2 = -3.4e38f;
        int i1 = lane, i2 = 0;
#pragma unroll
        for (int off = 32; off > 0; off >>= 1) {
            float om1 = __shfl_xor(m1, off);
            int   oi1 = __shfl_xor(i1, off);
            float om2 = __shfl_xor(m2, off);
            int   oi2 = __shfl_xor(i2, off);
            if (om1 > m1 || (om1 == m1 && oi1 < i1)) {
                if (m1 > om2 || (m1 == om2 && i1 < oi2)) { m2 = m1; i2 = i1; }
                else { m2 = om2; i2 = oi2; }
                m1 = om1; i1 = oi1;
            } else {
                if (om1 > m2 || (om1 == m2 && oi1 < i2)) { m2 = om1; i2 = oi1; }
            }
        }
        float pr = __expf(v - m1);
        float Z = pr;
#pragma unroll
        for (int off = 32; off > 0; off >>= 1) Z += __shfl_xor(Z, off);
        float invZ = 1.f / Z;
        pacc += pr * invZ;
        if (lane == 0) {
            float p1 = invZ;
            float p2 = __expf(m2 - m1) * invZ;
            float denom = p1 + p2 + 1e-6f;
            int n = n0 + t;
            out[2 * n + 0] = p1 / denom;
            out[2 * n + 1] = p2 / denom;
            out[OUT_IDX_OFF + 2 * n + 0] = (float)i1;
            out[OUT_IDX_OFF + 2 * n + 1] = (float)i2;
            atomicAdd(&scount[i1], 1.f);
            atomicAdd(&scount[i2], 1.f);
        }
    }
    atomicAdd(&sprob[lane], pacc);
    __syncthreads();

    if (tid < NEXP) {
        atomicAdd(&wsf[tid], sprob[tid]);
        atomicAdd(&wsf[NEXP + tid], scount[tid]);
    }

    // ---- last block computes aux loss + counts (fused router_finish) ----
    __threadfence();
    if (tid == 0) {
        unsigned prev = __hip_atomic_fetch_add((unsigned int*)(wsf + 2 * NEXP), 1u,
                                               __ATOMIC_ACQ_REL, __HIP_MEMORY_SCOPE_AGENT);
        slast = (prev == NBLK - 1) ? 1 : 0;
    }
    __syncthreads();
    if (slast && tid < NEXP) {
        const int e = tid;
        const float invN = 1.f / (float)NTOK;
        float ps = __hip_atomic_load(wsf + e, __ATOMIC_RELAXED, __HIP_MEMORY_SCOPE_AGENT);
        float cs = __hip_atomic_load(wsf + NEXP + e, __ATOMIC_RELAXED, __HIP_MEMORY_SCOPE_AGENT);
        out[OUT_CNT_OFF + e] = cs;
        float pv = ps * invN;
        float av = cs * invN;
        float v = pv * pv + av * av;
#pragma unroll
        for (int off = 32; off > 0; off >>= 1)
            v += __shfl_down(v, off);
        if (e == 0) out[OUT_AUX_OFF] = v * (float)NEXP;
    }
}

extern "C" void kernel_launch(void* const* d_in, const int* in_sizes, int n_in,
                              void* d_out, int out_size, void* d_ws, size_t ws_size,
                              hipStream_t stream)
{
    const float* x = (const float*)d_in[0];   // [4,4096,2048] f32
    const float* W = (const float*)d_in[1];   // [64,2048] f32
    float* out = (float*)d_out;
    float* wsf = (float*)d_ws;
    char* wq = (char*)d_ws + WS_W_OFF;        // W planes: 32 chunks x 24576 B = 768 KB

    wsplit_kernel<<<256, 64, 0, stream>>>(W, wq, wsf);   // also zeros accum+counter
    router_main<<<NBLK, NTHREADS, 0, stream>>>(x, wq, out, wsf);
}